// Round 3
// baseline (2634.854 us; speedup 1.0000x reference)
//
#include <hip/hip_runtime.h>
#include <math.h>

#define BS 8192
#define SL 49
#define FDIM 11
#define ROWS (BS*SL)

__device__ __forceinline__ float tanhshrink_f(float x) {
  // x - tanh(x), tanh = 1 - 2/(e^{2x}+1). Robust at +-inf of exp.
  float e = __expf(2.f * x);
  return (x - 1.f) + __fdividef(2.f, e + 1.f);
}

// ---------------- BN stats: sum / sumsq over (BS,SL) for features {0..7,10} ----
__global__ __launch_bounds__(256) void k_stats(const float* __restrict__ inp,
                                               double* __restrict__ gsum) {
  const int nblk = gridDim.x;
  const int per = (ROWS + nblk - 1) / nblk;
  const int r0 = blockIdx.x * per;
  int r1 = r0 + per; if (r1 > ROWS) r1 = ROWS;
  float s[9], q[9];
#pragma unroll
  for (int j = 0; j < 9; ++j) { s[j] = 0.f; q[j] = 0.f; }
  for (int r = r0 + threadIdx.x; r < r1; r += 256) {
    const float* row = inp + r * FDIM;
#pragma unroll
    for (int j = 0; j < 9; ++j) {
      float v = row[j < 8 ? j : 10];
      s[j] += v; q[j] += v * v;
    }
  }
#pragma unroll
  for (int j = 0; j < 9; ++j) {
    for (int off = 32; off; off >>= 1) {
      s[j] += __shfl_down(s[j], off);
      q[j] += __shfl_down(q[j], off);
    }
  }
  __shared__ float red[4][18];
  const int wid = threadIdx.x >> 6;
  const int lane = threadIdx.x & 63;
  if (lane == 0) {
#pragma unroll
    for (int j = 0; j < 9; ++j) { red[wid][j] = s[j]; red[wid][9 + j] = q[j]; }
  }
  __syncthreads();
  if (threadIdx.x < 18) {
    float t = red[0][threadIdx.x] + red[1][threadIdx.x] +
              red[2][threadIdx.x] + red[3][threadIdx.x];
    atomicAdd(&gsum[threadIdx.x], (double)t);
  }
}

// ---------------- finalize: BN params, layer-0 q, and TRANSPOSED weights ----
__global__ __launch_bounds__(256) void k_finalize(const double* __restrict__ gsum,
                           const float* __restrict__ gamma,
                           const float* __restrict__ beta,
                           const float* __restrict__ hidden,
                           const float* __restrict__ Wq,
                           const float* __restrict__ xe_w1,
                           const float* __restrict__ xe_w2,
                           const float* __restrict__ ye_w2,
                           const float* __restrict__ Wk,
                           float* __restrict__ bnp,
                           float* __restrict__ q0g,
                           float* __restrict__ xw1T,
                           float* __restrict__ xw2T,
                           float* __restrict__ yw2T,
                           float* __restrict__ wkT) {
  int tid = threadIdx.x;
  if (tid < 9) {
    const double N = (double)ROWS;
    double mean = gsum[tid] / N;
    double msq  = gsum[9 + tid] / N;
    float var = (float)(msq - mean * mean);
    float sc = gamma[tid] / sqrtf(var + 1e-5f);
    bnp[tid] = sc;
    bnp[9 + tid] = beta[tid] - (float)mean * sc;
  }
  // q0[s][i][c] = sum_k hidden[i][k] * Wq[l=0,s][k][c]
  int s = tid >> 7, i2 = (tid >> 6) & 1, c = tid & 63;
  const float* W = Wq + (s << 12);
#pragma unroll
  for (int ii = 0; ii < 2; ++ii) {
    int i = i2 + 2 * ii;
    float a = 0.f;
    for (int k = 0; k < 64; ++k) a += hidden[i * 64 + k] * W[k * 64 + c];
    q0g[s * 256 + i * 64 + c] = a;
  }
  // transposes: T[c][k] = W[k][c]
  for (int i = tid; i < 512; i += 256)  { int cc = i >> 3,  k = i & 7;  xw1T[i] = xe_w1[k * 64 + cc]; }
  for (int i = tid; i < 4096; i += 256) { int cc = i >> 6,  k = i & 63; xw2T[i] = xe_w2[k * 64 + cc]; }
  for (int i = tid; i < 4096; i += 256) { int cc = i >> 6,  k = i & 63; yw2T[i] = ye_w2[k * 64 + cc]; }
  for (int i = tid; i < 16384; i += 256) {
    int ls = i >> 12, r = i & 4095, cc = r >> 6, k = r & 63;
    wkT[i] = Wk[ls * 4096 + k * 64 + cc];
  }
}

// ---------------- mega kernel: one block per (batch, stream) ----------------
// LDS-broadcast fix: projection matmuls (embed1/embed2/K) use lane=row,
// wave=16-col chunk, weights via wave-uniform (SGPR) loads of transposed
// weights. Activations become distinct-address ds_read_b128 (read once/row)
// instead of wave-broadcast reads. scores/T/Wv/Wo/cross unchanged.
// LDS 40280 B -> 4 blocks/CU.
__global__ __launch_bounds__(256, 4) void k_mega(
    const float* __restrict__ inp, const float* __restrict__ dists,
    const float* __restrict__ bnp, const float* __restrict__ q0g,
    const float* __restrict__ xw1T, const float* __restrict__ xe_b1,
    const float* __restrict__ xw2T, const float* __restrict__ xe_b2,
    const float* __restrict__ ye_w1, const float* __restrict__ ye_b1,
    const float* __restrict__ yw2T, const float* __restrict__ ye_b2,
    const float* __restrict__ learnable_y, const float* __restrict__ hidden_tokens,
    const float* __restrict__ Wq, const float* __restrict__ wkT,
    const float* __restrict__ Wv, const float* __restrict__ Wo,
    const float* __restrict__ Wq2, const float* __restrict__ Wk2,
    const float* __restrict__ Wv2, const float* __restrict__ Wo2,
    float* __restrict__ enc)
{
  __shared__ float raw[49][12];
  __shared__ float cs8T[8][52];   // [p][t]: per-lane distinct reads, conflict-free
  __shared__ float embs[49 * 68]; // emb, stride 68 (17 float4-slots, odd -> spread)
  __shared__ float KB[49][68];    // h1, then K (rope'd), then T, then k2/v2
  __shared__ float scb[32][52];   // softmax probs
  __shared__ float Hs[4][64];
  __shared__ float qb[4][64];
  __shared__ float db[48];
  __shared__ float bnl[18];
  __shared__ float q2[64];
  __shared__ float o1[64];
  __shared__ float a2[32];

  const int tid  = threadIdx.x;
  const int lane = tid & 63;
  const int grp  = tid >> 6;
  const int wg   = __builtin_amdgcn_readfirstlane(grp);  // provably wave-uniform
  const int b    = blockIdx.x >> 1;
  const int s    = blockIdx.x & 1;
  const float scale = 0.35355339059327373f;  // 1/sqrt(8)

  // ---- load input rows, bn params, dists
  for (int i = tid; i < 49 * FDIM; i += 256) raw[i / FDIM][i % FDIM] = inp[b * (49*FDIM) + i];
  if (tid < 18) bnl[tid] = bnp[tid];
  if (tid >= 64 && tid < 112) db[tid - 64] = dists[b * 49 + (tid - 64)];
  __syncthreads();   // B1

  // ---- rope trig from RAW features 8,9 ; BN features {0..7,10} in place
  if (tid < 49) {
    float x = raw[tid][8], y = raw[tid][9];
    cs8T[0][tid] = cosf(10.f * x); cs8T[1][tid] = cosf(10.f * y);
    cs8T[2][tid] = cosf(x);        cs8T[3][tid] = cosf(y);
    cs8T[4][tid] = sinf(10.f * x); cs8T[5][tid] = sinf(10.f * y);
    cs8T[6][tid] = sinf(x);        cs8T[7][tid] = sinf(y);
  }
  for (int i = tid; i < 441; i += 256) {   // 49*9
    int t = i / 9, j = i - t * 9;
    int f = (j < 8) ? j : 10;
    raw[t][f] = raw[t][f] * bnl[j] + bnl[9 + j];
  }
  __syncthreads();   // B2

  if (s == 0 && tid < 10) enc[b * 138 + 128 + tid] = raw[48][tid];

  // ---- embed layer 1 -> KB (h1). lane=row, wave wg = cols 16wg..16wg+15
  if (s == 0) {
    if (lane < 49) {
      float4 r0 = *(const float4*)&raw[lane][0];
      float4 r1 = *(const float4*)&raw[lane][4];
      float h[16];
#pragma unroll
      for (int ci = 0; ci < 16; ++ci) {
        int c = wg * 16 + ci;
        const float* w = xw1T + c * 8;          // uniform -> s_load
        float a = xe_b1[c]
                + r0.x * w[0] + r0.y * w[1] + r0.z * w[2] + r0.w * w[3]
                + r1.x * w[4] + r1.y * w[5] + r1.z * w[6] + r1.w * w[7];
        h[ci] = tanhshrink_f(a);
      }
#pragma unroll
      for (int i = 0; i < 4; ++i)
        *(float4*)&KB[lane][wg * 16 + 4 * i] = make_float4(h[4*i], h[4*i+1], h[4*i+2], h[4*i+3]);
    }
  } else {
    if (lane < 48) {
      float ry = raw[lane][10];
      float h[16];
#pragma unroll
      for (int ci = 0; ci < 16; ++ci) {
        int c = wg * 16 + ci;
        h[ci] = tanhshrink_f(ry * ye_w1[c] + ye_b1[c]);   // uniform weights
      }
#pragma unroll
      for (int i = 0; i < 4; ++i)
        *(float4*)&KB[lane][wg * 16 + 4 * i] = make_float4(h[4*i], h[4*i+1], h[4*i+2], h[4*i+3]);
    }
  }
  __syncthreads();   // B2a: h1 col-chunks from all waves published

  // ---- embed layer 2 -> embs. lane=row, wave=col chunk, SGPR weights
  {
    const int nrow = (s == 0) ? 49 : 48;
    const float* WT = (s == 0) ? xw2T : yw2T;
    const float* bb = (s == 0) ? xe_b2 : ye_b2;
    if (lane < nrow) {
      float4 h[16];
#pragma unroll
      for (int g = 0; g < 16; ++g) h[g] = *(const float4*)&KB[lane][4 * g];
      float o[16];
#pragma unroll
      for (int ci = 0; ci < 16; ++ci) {
        int c = wg * 16 + ci;
        const float* w = WT + c * 64;           // uniform, contiguous 256B
        float a = bb[c];
#pragma unroll
        for (int g = 0; g < 16; ++g) {
          float4 wv = *(const float4*)&w[4 * g];
          a += h[g].x * wv.x + h[g].y * wv.y + h[g].z * wv.z + h[g].w * wv.w;
        }
        o[ci] = a;
      }
#pragma unroll
      for (int i = 0; i < 4; ++i)
        *(float4*)&embs[lane * 68 + wg * 16 + 4 * i] = make_float4(o[4*i], o[4*i+1], o[4*i+2], o[4*i+3]);
    }
    if (s == 1 && tid < 64) embs[48 * 68 + lane] = learnable_y[lane];
  }
  Hs[grp][lane] = hidden_tokens[grp * 64 + lane];
  __syncthreads();   // B2b: embs published

  // ---- 2 self-attention layers
#pragma unroll 1
  for (int l = 0; l < 2; ++l) {
    const float* Wv_p = Wv + ((l * 2 + s) << 12);
    const float* Wo_p = Wo + ((l * 2 + s) << 12);
    // q: layer 0 precomputed; layer 1 = H @ Wq (wave-local small matmul)
    if (l == 0) {
      qb[grp][lane] = q0g[s * 256 + tid];
    } else {
      const float* Wq_p = Wq + ((l * 2 + s) << 12);
      float a = 0.f;
      for (int k = 0; k < 64; k += 4) {
        float4 hv = *(const float4*)&Hs[grp][k];
        a += hv.x * Wq_p[(k + 0) * 64 + lane] + hv.y * Wq_p[(k + 1) * 64 + lane]
           + hv.z * Wq_p[(k + 2) * 64 + lane] + hv.w * Wq_p[(k + 3) * 64 + lane];
      }
      qb[grp][lane] = a;
    }
    // K = rope(ctx @ Wk): lane=row (48), wave=col chunk, SGPR weights
    if (lane < 48) {
      float4 e[16];
#pragma unroll
      for (int g = 0; g < 16; ++g) e[g] = *(const float4*)&embs[lane * 68 + 4 * g];
      float kc[16];
      const float* WTl = wkT + ((l * 2 + s) << 12);
#pragma unroll
      for (int ci = 0; ci < 16; ++ci) {
        int c = wg * 16 + ci;
        const float* w = WTl + c * 64;          // uniform, contiguous
        float a = 0.f;
#pragma unroll
        for (int g = 0; g < 16; ++g) {
          float4 wv = *(const float4*)&w[4 * g];
          a += e[g].x * wv.x + e[g].y * wv.y + e[g].z * wv.z + e[g].w * wv.w;
        }
        kc[ci] = a;
      }
      // rope: pairs are thread-local now
      float ko[16];
#pragma unroll
      for (int i = 0; i < 8; ++i) {
        int p = (8 * wg + i) & 3;
        float co = cs8T[p][lane], si = cs8T[4 + p][lane];
        ko[2*i]   = co * kc[2*i] - si * kc[2*i+1];
        ko[2*i+1] = si * kc[2*i] + co * kc[2*i+1];
      }
#pragma unroll
      for (int i = 0; i < 4; ++i)
        *(float4*)&KB[lane][wg * 16 + 4 * i] = make_float4(ko[4*i], ko[4*i+1], ko[4*i+2], ko[4*i+3]);
    }
    __syncthreads();   // B3: K + q published
    // scores + softmax fused (unchanged)
    {
      const int t0 = tid & 7;
      const int i  = (tid >> 3) & 3;
      const int h  = tid >> 5;
      const int r  = tid >> 3;
      float4 qa = *(const float4*)&qb[i][h * 8];
      float4 qc = *(const float4*)&qb[i][h * 8 + 4];
      float v[6];
#pragma unroll
      for (int j = 0; j < 6; ++j) {
        int t = t0 + 8 * j;
        float4 ka = *(const float4*)&KB[t][h * 8];
        float4 kc = *(const float4*)&KB[t][h * 8 + 4];
        float a = qa.x * ka.x + qa.y * ka.y + qa.z * ka.z + qa.w * ka.w
                + qc.x * kc.x + qc.y * kc.y + qc.z * kc.z + qc.w * kc.w;
        v[j] = a * scale - db[t];
      }
      float m = fmaxf(fmaxf(fmaxf(v[0], v[1]), fmaxf(v[2], v[3])), fmaxf(v[4], v[5]));
      m = fmaxf(m, __shfl_xor(m, 1));
      m = fmaxf(m, __shfl_xor(m, 2));
      m = fmaxf(m, __shfl_xor(m, 4));
      float sum = 0.f;
#pragma unroll
      for (int j = 0; j < 6; ++j) { v[j] = __expf(v[j] - m); sum += v[j]; }
      sum += __shfl_xor(sum, 1);
      sum += __shfl_xor(sum, 2);
      sum += __shfl_xor(sum, 4);
      float inv = 1.f / sum;
#pragma unroll
      for (int j = 0; j < 6; ++j) scb[r][t0 + 8 * j] = v[j] * inv;
    }
    __syncthreads();   // B4: probs published; fences KB reads before T writes
    // T = a @ ctx  (32 x 64), rows grp+4m -> KB (wave-local mod-4 rows)
    {
      float acc[8];
#pragma unroll
      for (int m = 0; m < 8; ++m) acc[m] = 0.f;
      for (int tt = 0; tt < 48; tt += 4) {
        float e0 = embs[(tt + 0) * 68 + lane], e1 = embs[(tt + 1) * 68 + lane];
        float e2 = embs[(tt + 2) * 68 + lane], e3 = embs[(tt + 3) * 68 + lane];
#pragma unroll
        for (int m = 0; m < 8; ++m) {
          float4 sc4 = *(const float4*)&scb[grp + 4 * m][tt];
          acc[m] += sc4.x * e0 + sc4.y * e1 + sc4.z * e2 + sc4.w * e3;
        }
      }
#pragma unroll
      for (int m = 0; m < 8; ++m) KB[grp + 4 * m][lane] = acc[m];
    }
    // no barrier: wave grp reads exactly rows ≡ grp (mod 4) it just wrote
    {
      const int r = ((lane >> 3) << 2) + grp;
      float a = 0.f;
      for (int c = 0; c < 64; c += 4) {
        float4 tv = *(const float4*)&KB[r][c];
        a += tv.x * Wv_p[(c + 0) * 64 + lane] + tv.y * Wv_p[(c + 1) * 64 + lane]
           + tv.z * Wv_p[(c + 2) * 64 + lane] + tv.w * Wv_p[(c + 3) * 64 + lane];
      }
      qb[grp][lane] = a;
    }
    // no barrier: qb row grp wave-local
    {
      float a = Hs[grp][lane];
      for (int k = 0; k < 64; k += 4) {
        float4 av = *(const float4*)&qb[grp][k];
        a += av.x * Wo_p[(k + 0) * 64 + lane] + av.y * Wo_p[(k + 1) * 64 + lane]
           + av.z * Wo_p[(k + 2) * 64 + lane] + av.w * Wo_p[(k + 3) * 64 + lane];
      }
      Hs[grp][lane] = a;
    }
    if (l == 0) __syncthreads();   // B5a: Wv reads of KB done before l=1 K writes
  }

  // ---- final cross attention
  const float* Wq2_p = Wq2 + (s << 12);
  const float* Wk2_p = Wk2 + (s << 12);
  const float* Wv2_p = Wv2 + (s << 12);
  const float* Wo2_p = Wo2 + (s << 12);
  if (tid < 64) {
    float a = 0.f;
    for (int k = 0; k < 64; k += 4) {
      float4 cv = *(const float4*)&embs[48 * 68 + k];
      a += cv.x * Wq2_p[(k + 0) * 64 + lane] + cv.y * Wq2_p[(k + 1) * 64 + lane]
         + cv.z * Wq2_p[(k + 2) * 64 + lane] + cv.w * Wq2_p[(k + 3) * 64 + lane];
    }
    float other = __shfl_xor(a, 1);
    int p = (lane >> 1) & 3;
    float co = cs8T[p][48], si = cs8T[4 + p][48];
    q2[lane] = (lane & 1) ? (si * other + co * a) : (co * a - si * other);
  }
  {
    float aK = 0.f, aV = 0.f;
    for (int k = 0; k < 64; k += 4) {
      float4 hv = *(const float4*)&Hs[grp][k];
      aK += hv.x * Wk2_p[(k + 0) * 64 + lane] + hv.y * Wk2_p[(k + 1) * 64 + lane]
          + hv.z * Wk2_p[(k + 2) * 64 + lane] + hv.w * Wk2_p[(k + 3) * 64 + lane];
      aV += hv.x * Wv2_p[(k + 0) * 64 + lane] + hv.y * Wv2_p[(k + 1) * 64 + lane]
          + hv.z * Wv2_p[(k + 2) * 64 + lane] + hv.w * Wv2_p[(k + 3) * 64 + lane];
    }
    KB[grp][lane] = aK;      // k2 rows 0..3
    KB[8 + grp][lane] = aV;  // v2 rows 8..11
  }
  __syncthreads();   // B5: k2/v2 + q2 published for wave 0
  if (tid < 32) {
    int h = tid >> 2, i = tid & 3;
    float a = 0.f;
#pragma unroll
    for (int d = 0; d < 8; ++d) a += q2[h * 8 + d] * KB[i][h * 8 + d];
    a *= scale;
    float m = fmaxf(a, __shfl_xor(a, 1));
    m = fmaxf(m, __shfl_xor(m, 2));
    float e = __expf(a - m);
    float sum = e + __shfl_xor(e, 1);
    sum += __shfl_xor(sum, 2);
    a2[tid] = e / sum;
  }
  // wave-0 local from here
  if (tid < 64) {
    int h = lane >> 3;
    float a = 0.f;
#pragma unroll
    for (int i = 0; i < 4; ++i) a += a2[h * 4 + i] * KB[8 + i][lane];
    o1[lane] = a;
  }
  if (tid < 64) {
    float a = 0.f;
    for (int k = 0; k < 64; k += 4) {
      float4 ov = *(const float4*)&o1[k];
      a += ov.x * Wo2_p[(k + 0) * 64 + lane] + ov.y * Wo2_p[(k + 1) * 64 + lane]
         + ov.z * Wo2_p[(k + 2) * 64 + lane] + ov.w * Wo2_p[(k + 3) * 64 + lane];
    }
    enc[b * 138 + s * 64 + lane] = a;
  }
}

// ---------------- decoder: enc(138) -> 512 -> 256 -> 1, 8 batches/block ----
__global__ __launch_bounds__(256, 5) void k_dec(
    const float* __restrict__ enc,
    const float* __restrict__ w0, const float* __restrict__ b0,
    const float* __restrict__ w1, const float* __restrict__ b1,
    const float* __restrict__ w2, const float* __restrict__ b2,
    float* __restrict__ out)
{
  __shared__ float encs[8][140];
  __shared__ float h0s[8][512];
  __shared__ float h1s[8][256];
  const int tid = threadIdx.x;
  const int rb = blockIdx.x * 8;

  for (int i = tid; i < 8 * 138; i += 256) {
    int r = i / 138, k = i - r * 138;
    encs[r][k] = enc[(rb + r) * 138 + k];
  }
  __syncthreads();
  {
    float acc0[8], acc1[8];
    const float bb0 = b0[tid], bb1 = b0[tid + 256];
#pragma unroll
    for (int r = 0; r < 8; ++r) { acc0[r] = bb0; acc1[r] = bb1; }
    for (int k = 0; k < 136; k += 4) {
      float wa0 = w0[(k + 0) * 512 + tid], wa1 = w0[(k + 1) * 512 + tid];
      float wa2 = w0[(k + 2) * 512 + tid], wa3 = w0[(k + 3) * 512 + tid];
      float wb0 = w0[(k + 0) * 512 + tid + 256], wb1 = w0[(k + 1) * 512 + tid + 256];
      float wb2 = w0[(k + 2) * 512 + tid + 256], wb3 = w0[(k + 3) * 512 + tid + 256];
#pragma unroll
      for (int r = 0; r < 8; ++r) {
        float4 ev = *(const float4*)&encs[r][k];
        acc0[r] += ev.x * wa0 + ev.y * wa1 + ev.z * wa2 + ev.w * wa3;
        acc1[r] += ev.x * wb0 + ev.y * wb1 + ev.z * wb2 + ev.w * wb3;
      }
    }
    for (int k = 136; k < 138; ++k) {
      float wa = w0[k * 512 + tid], wb = w0[k * 512 + tid + 256];
#pragma unroll
      for (int r = 0; r < 8; ++r) {
        float e = encs[r][k];
        acc0[r] += e * wa; acc1[r] += e * wb;
      }
    }
#pragma unroll
    for (int r = 0; r < 8; ++r) {
      h0s[r][tid] = tanhshrink_f(acc0[r]);
      h0s[r][tid + 256] = tanhshrink_f(acc1[r]);
    }
  }
  __syncthreads();
  {
    float acc[8];
    const float bb = b1[tid];
#pragma unroll
    for (int r = 0; r < 8; ++r) acc[r] = bb;
    for (int k = 0; k < 512; k += 4) {
      float ww0 = w1[(k + 0) * 256 + tid], ww1 = w1[(k + 1) * 256 + tid];
      float ww2 = w1[(k + 2) * 256 + tid], ww3 = w1[(k + 3) * 256 + tid];
#pragma unroll
      for (int r = 0; r < 8; ++r) {
        float4 hv = *(const float4*)&h0s[r][k];
        acc[r] += hv.x * ww0 + hv.y * ww1 + hv.z * ww2 + hv.w * ww3;
      }
    }
#pragma unroll
    for (int r = 0; r < 8; ++r) h1s[r][tid] = tanhshrink_f(acc[r]);
  }
  __syncthreads();
  {
    int r = tid >> 5, l32 = tid & 31;
    float a = 0.f;
#pragma unroll
    for (int kk = 0; kk < 8; ++kk) {
      int k = l32 + 32 * kk;
      a += h1s[r][k] * w2[k];
    }
    for (int off = 16; off; off >>= 1) a += __shfl_down(a, off, 32);
    if (l32 == 0) out[rb + r] = a + b2[0];
  }
}

extern "C" void kernel_launch(void* const* d_in, const int* in_sizes, int n_in,
                              void* d_out, int out_size, void* d_ws, size_t ws_size,
                              hipStream_t stream) {
  const float* inp        = (const float*)d_in[0];
  const float* dists      = (const float*)d_in[1];
  const float* bn_gamma   = (const float*)d_in[3];
  const float* bn_beta    = (const float*)d_in[4];
  const float* xe_w1      = (const float*)d_in[5];
  const float* xe_b1      = (const float*)d_in[6];
  const float* xe_w2      = (const float*)d_in[7];
  const float* xe_b2      = (const float*)d_in[8];
  const float* ye_w1      = (const float*)d_in[9];
  const float* ye_b1      = (const float*)d_in[10];
  const float* ye_w2      = (const float*)d_in[11];
  const float* ye_b2      = (const float*)d_in[12];
  const float* learnable  = (const float*)d_in[13];
  const float* hidden     = (const float*)d_in[14];
  const float* Wq         = (const float*)d_in[15];
  const float* Wk         = (const float*)d_in[16];
  const float* Wv         = (const float*)d_in[17];
  const float* Wo         = (const float*)d_in[18];
  const float* Wq2        = (const float*)d_in[19];
  const float* Wk2        = (const float*)d_in[20];
  const float* Wv2        = (const float*)d_in[21];
  const float* Wo2        = (const float*)d_in[22];
  const float* dec_w0     = (const float*)d_in[23];
  const float* dec_b0     = (const float*)d_in[24];
  const float* dec_w1     = (const float*)d_in[25];
  const float* dec_b1     = (const float*)d_in[26];
  const float* dec_w2     = (const float*)d_in[27];
  const float* dec_b2     = (const float*)d_in[28];

  double* gsum = (double*)d_ws;                       // 18 doubles @ 0
  float*  bnp  = (float*)((char*)d_ws + 256);         // 18 floats
  float*  q0g  = (float*)((char*)d_ws + 512);         // 512 floats
  float*  enc  = (float*)((char*)d_ws + 2560);        // 8192*138 floats -> ends 4524544
  float*  xw1T = (float*)((char*)d_ws + 4524544);     // 512 floats   (2048 B)
  float*  xw2T = (float*)((char*)d_ws + 4526592);     // 4096 floats  (16384 B)
  float*  yw2T = (float*)((char*)d_ws + 4542976);     // 4096 floats
  float*  wkT  = (float*)((char*)d_ws + 4559360);     // 16384 floats (65536 B) -> ends 4624896

  hipMemsetAsync(d_ws, 0, 256, stream);
  k_stats   <<<512, 256, 0, stream>>>(inp, gsum);
  k_finalize<<<1, 256, 0, stream>>>(gsum, bn_gamma, bn_beta, hidden, Wq,
                                    xe_w1, xe_w2, ye_w2, Wk,
                                    bnp, q0g, xw1T, xw2T, yw2T, wkT);
  k_mega    <<<BS * 2, 256, 0, stream>>>(inp, dists, bnp, q0g,
                                         xw1T, xe_b1, xw2T, xe_b2,
                                         ye_w1, ye_b1, yw2T, ye_b2,
                                         learnable, hidden,
                                         Wq, wkT, Wv, Wo, Wq2, Wk2, Wv2, Wo2, enc);
  k_dec     <<<BS / 8, 256, 0, stream>>>(enc, dec_w0, dec_b0, dec_w1, dec_b1,
                                         dec_w2, dec_b2, (float*)d_out);
}

// Round 4
// 871.535 us; speedup vs baseline: 3.0232x; 3.0232x over previous
//
#include <hip/hip_runtime.h>
#include <math.h>

#define BS 8192
#define SL 49
#define FDIM 11
#define ROWS (BS*SL)

__device__ __forceinline__ float tanhshrink_f(float x) {
  // x - tanh(x), tanh = 1 - 2/(e^{2x}+1). Robust at +-inf of exp.
  float e = __expf(2.f * x);
  return (x - 1.f) + __fdividef(2.f, e + 1.f);
}

// ---------------- BN stats: sum / sumsq over (BS,SL) for features {0..7,10} ----
__global__ __launch_bounds__(256) void k_stats(const float* __restrict__ inp,
                                               double* __restrict__ gsum) {
  const int nblk = gridDim.x;
  const int per = (ROWS + nblk - 1) / nblk;
  const int r0 = blockIdx.x * per;
  int r1 = r0 + per; if (r1 > ROWS) r1 = ROWS;
  float s[9], q[9];
#pragma unroll
  for (int j = 0; j < 9; ++j) { s[j] = 0.f; q[j] = 0.f; }
  for (int r = r0 + threadIdx.x; r < r1; r += 256) {
    const float* row = inp + r * FDIM;
#pragma unroll
    for (int j = 0; j < 9; ++j) {
      float v = row[j < 8 ? j : 10];
      s[j] += v; q[j] += v * v;
    }
  }
#pragma unroll
  for (int j = 0; j < 9; ++j) {
    for (int off = 32; off; off >>= 1) {
      s[j] += __shfl_down(s[j], off);
      q[j] += __shfl_down(q[j], off);
    }
  }
  __shared__ float red[4][18];
  const int wid = threadIdx.x >> 6;
  const int lane = threadIdx.x & 63;
  if (lane == 0) {
#pragma unroll
    for (int j = 0; j < 9; ++j) { red[wid][j] = s[j]; red[wid][9 + j] = q[j]; }
  }
  __syncthreads();
  if (threadIdx.x < 18) {
    float t = red[0][threadIdx.x] + red[1][threadIdx.x] +
              red[2][threadIdx.x] + red[3][threadIdx.x];
    atomicAdd(&gsum[threadIdx.x], (double)t);
  }
}

// ------- finalize: BN params, layer-0 q, and chunk-packed weight layouts -------
// xw1T[c][k] (64x8); we2[s][kc][c][kk] = W2[4kc+kk][c]; wk4[ls][kc][c][kk].
// Chunk layout puts one wave's 16-col x 4-k weight slice in 256 contiguous B
// at a wave-uniform address -> s_load_dwordx16 on the scalar pipe.
__global__ __launch_bounds__(256) void k_finalize(const double* __restrict__ gsum,
                           const float* __restrict__ gamma,
                           const float* __restrict__ beta,
                           const float* __restrict__ hidden,
                           const float* __restrict__ Wq,
                           const float* __restrict__ xe_w1,
                           const float* __restrict__ xe_w2,
                           const float* __restrict__ ye_w2,
                           const float* __restrict__ Wk,
                           float* __restrict__ bnp,
                           float* __restrict__ q0g,
                           float* __restrict__ xw1T,
                           float* __restrict__ we2,
                           float* __restrict__ wk4) {
  int tid = threadIdx.x;
  if (tid < 9) {
    const double N = (double)ROWS;
    double mean = gsum[tid] / N;
    double msq  = gsum[9 + tid] / N;
    float var = (float)(msq - mean * mean);
    float sc = gamma[tid] / sqrtf(var + 1e-5f);
    bnp[tid] = sc;
    bnp[9 + tid] = beta[tid] - (float)mean * sc;
  }
  // q0[s][i][c] = sum_k hidden[i][k] * Wq[l=0,s][k][c]
  int s = tid >> 7, i2 = (tid >> 6) & 1, c = tid & 63;
  const float* W = Wq + (s << 12);
#pragma unroll
  for (int ii = 0; ii < 2; ++ii) {
    int i = i2 + 2 * ii;
    float a = 0.f;
    for (int k = 0; k < 64; ++k) a += hidden[i * 64 + k] * W[k * 64 + c];
    q0g[s * 256 + i * 64 + c] = a;
  }
  for (int i = tid; i < 512; i += 256)  { int cc = i >> 3, k = i & 7; xw1T[i] = xe_w1[k * 64 + cc]; }
  for (int i = tid; i < 8192; i += 256) {
    int ss = i >> 12, r = i & 4095, kc = r >> 8, cc = (r >> 2) & 63, kk = r & 3;
    const float* W2 = ss ? ye_w2 : xe_w2;
    we2[i] = W2[(4 * kc + kk) * 64 + cc];
  }
  for (int i = tid; i < 16384; i += 256) {
    int ls = i >> 12, r = i & 4095, kc = r >> 8, cc = (r >> 2) & 63, kk = r & 3;
    wk4[i] = Wk[ls * 4096 + (4 * kc + kk) * 64 + cc];
  }
}

// ---------------- mega kernel: one block per (batch, stream) ----------------
// Broadcast-LDS fix, register-frugal version: embed2 and K-proj use lane=row,
// wave=16-col chunk, k chunked by 4: per chunk ONE distinct-address
// ds_read_b128 (the lane's own activation floats) + 64 weight floats via
// wave-uniform s_load (SMEM pipe). Max live register array: o[16].
// All other phases and the barrier structure are the verified round-2/3 code.
__global__ __launch_bounds__(256, 4) void k_mega(
    const float* __restrict__ inp, const float* __restrict__ dists,
    const float* __restrict__ bnp, const float* __restrict__ q0g,
    const float* __restrict__ xw1T, const float* __restrict__ xe_b1,
    const float* __restrict__ we2, const float* __restrict__ xe_b2,
    const float* __restrict__ ye_w1, const float* __restrict__ ye_b1,
    const float* __restrict__ ye_b2,
    const float* __restrict__ learnable_y, const float* __restrict__ hidden_tokens,
    const float* __restrict__ Wq, const float* __restrict__ wk4,
    const float* __restrict__ Wv, const float* __restrict__ Wo,
    const float* __restrict__ Wq2, const float* __restrict__ Wk2,
    const float* __restrict__ Wv2, const float* __restrict__ Wo2,
    float* __restrict__ enc)
{
  __shared__ float raw[49][12];
  __shared__ float cs8T[8][52];   // [p][t]: per-lane distinct reads
  __shared__ float embs[49 * 68]; // emb, stride 68
  __shared__ float KB[49][68];    // h1, then K (rope'd), then T, then k2/v2
  __shared__ float scb[32][52];   // softmax probs
  __shared__ float Hs[4][64];
  __shared__ float qb[4][64];
  __shared__ float db[48];
  __shared__ float bnl[18];
  __shared__ float q2[64];
  __shared__ float o1[64];
  __shared__ float a2[32];

  const int tid  = threadIdx.x;
  const int lane = tid & 63;
  const int grp  = tid >> 6;
  const int wg   = __builtin_amdgcn_readfirstlane(grp);  // provably wave-uniform
  const int b    = blockIdx.x >> 1;
  const int s    = blockIdx.x & 1;
  const float scale = 0.35355339059327373f;  // 1/sqrt(8)

  // ---- load input rows, bn params, dists
  for (int i = tid; i < 49 * FDIM; i += 256) raw[i / FDIM][i % FDIM] = inp[b * (49*FDIM) + i];
  if (tid < 18) bnl[tid] = bnp[tid];
  if (tid >= 64 && tid < 112) db[tid - 64] = dists[b * 49 + (tid - 64)];
  __syncthreads();   // B1

  // ---- rope trig from RAW features 8,9 ; BN features {0..7,10} in place
  if (tid < 49) {
    float x = raw[tid][8], y = raw[tid][9];
    cs8T[0][tid] = cosf(10.f * x); cs8T[1][tid] = cosf(10.f * y);
    cs8T[2][tid] = cosf(x);        cs8T[3][tid] = cosf(y);
    cs8T[4][tid] = sinf(10.f * x); cs8T[5][tid] = sinf(10.f * y);
    cs8T[6][tid] = sinf(x);        cs8T[7][tid] = sinf(y);
  }
  for (int i = tid; i < 441; i += 256) {   // 49*9
    int t = i / 9, j = i - t * 9;
    int f = (j < 8) ? j : 10;
    raw[t][f] = raw[t][f] * bnl[j] + bnl[9 + j];
  }
  __syncthreads();   // B2

  if (s == 0 && tid < 10) enc[b * 138 + 128 + tid] = raw[48][tid];

  // ---- embed layer 1 -> KB (h1). lane=row, wave wg = cols 16wg..16wg+15
  if (s == 0) {
    if (lane < 49) {
      float4 r0 = *(const float4*)&raw[lane][0];
      float4 r1 = *(const float4*)&raw[lane][4];
      const float* w = xw1T + wg * 128;   // 16 cols x 8 k, contiguous, uniform
      float h[16];
#pragma unroll
      for (int ci = 0; ci < 16; ++ci) {
        float a = xe_b1[wg * 16 + ci]
                + r0.x * w[ci*8+0] + r0.y * w[ci*8+1] + r0.z * w[ci*8+2] + r0.w * w[ci*8+3]
                + r1.x * w[ci*8+4] + r1.y * w[ci*8+5] + r1.z * w[ci*8+6] + r1.w * w[ci*8+7];
        h[ci] = tanhshrink_f(a);
      }
#pragma unroll
      for (int i = 0; i < 4; ++i)
        *(float4*)&KB[lane][wg * 16 + 4 * i] = make_float4(h[4*i], h[4*i+1], h[4*i+2], h[4*i+3]);
    }
  } else {
    if (lane < 48) {
      float ry = raw[lane][10];
      float h[16];
#pragma unroll
      for (int ci = 0; ci < 16; ++ci)
        h[ci] = tanhshrink_f(ry * ye_w1[wg * 16 + ci] + ye_b1[wg * 16 + ci]);
#pragma unroll
      for (int i = 0; i < 4; ++i)
        *(float4*)&KB[lane][wg * 16 + 4 * i] = make_float4(h[4*i], h[4*i+1], h[4*i+2], h[4*i+3]);
    }
  }
  __syncthreads();   // B2a: h1 col-chunks from all waves published

  // ---- embed layer 2 -> embs. lane=row, chunked k, SMEM weights
  {
    const int nrow = (s == 0) ? 49 : 48;
    const float* WE = we2 + (s << 12);
    const float* bb = (s == 0) ? xe_b2 : ye_b2;
    if (lane < nrow) {
      float o[16];
#pragma unroll
      for (int ci = 0; ci < 16; ++ci) o[ci] = bb[wg * 16 + ci];
      for (int kc = 0; kc < 16; ++kc) {
        float4 e = *(const float4*)&KB[lane][kc * 4];     // distinct per lane
        const float* w = WE + (kc << 8) + (wg << 6);      // uniform 256 B
#pragma unroll
        for (int ci = 0; ci < 16; ++ci)
          o[ci] += e.x * w[ci*4+0] + e.y * w[ci*4+1] + e.z * w[ci*4+2] + e.w * w[ci*4+3];
      }
#pragma unroll
      for (int i = 0; i < 4; ++i)
        *(float4*)&embs[lane * 68 + wg * 16 + 4 * i] = make_float4(o[4*i], o[4*i+1], o[4*i+2], o[4*i+3]);
    }
    if (s == 1 && tid < 64) embs[48 * 68 + lane] = learnable_y[lane];
  }
  Hs[grp][lane] = hidden_tokens[grp * 64 + lane];
  __syncthreads();   // B2b: embs published

  // ---- 2 self-attention layers
#pragma unroll 1
  for (int l = 0; l < 2; ++l) {
    const float* Wv_p = Wv + ((l * 2 + s) << 12);
    const float* Wo_p = Wo + ((l * 2 + s) << 12);
    // q: layer 0 precomputed; layer 1 = H @ Wq (wave-local small matmul)
    if (l == 0) {
      qb[grp][lane] = q0g[s * 256 + tid];
    } else {
      const float* Wq_p = Wq + ((l * 2 + s) << 12);
      float a = 0.f;
      for (int k = 0; k < 64; k += 4) {
        float4 hv = *(const float4*)&Hs[grp][k];
        a += hv.x * Wq_p[(k + 0) * 64 + lane] + hv.y * Wq_p[(k + 1) * 64 + lane]
           + hv.z * Wq_p[(k + 2) * 64 + lane] + hv.w * Wq_p[(k + 3) * 64 + lane];
      }
      qb[grp][lane] = a;
    }
    // K = rope(ctx @ Wk): lane=row, chunked k, SMEM weights
    if (lane < 48) {
      float o[16];
#pragma unroll
      for (int ci = 0; ci < 16; ++ci) o[ci] = 0.f;
      const float* WK = wk4 + ((l * 2 + s) << 12);
      for (int kc = 0; kc < 16; ++kc) {
        float4 e = *(const float4*)&embs[lane * 68 + kc * 4];  // distinct per lane
        const float* w = WK + (kc << 8) + (wg << 6);           // uniform 256 B
#pragma unroll
        for (int ci = 0; ci < 16; ++ci)
          o[ci] += e.x * w[ci*4+0] + e.y * w[ci*4+1] + e.z * w[ci*4+2] + e.w * w[ci*4+3];
      }
      // rope: pairs thread-local; pair index 8wg+i -> p = i&3
      float ko[16];
#pragma unroll
      for (int i = 0; i < 8; ++i) {
        int p = i & 3;
        float co = cs8T[p][lane], si = cs8T[4 + p][lane];
        ko[2*i]   = co * o[2*i] - si * o[2*i+1];
        ko[2*i+1] = si * o[2*i] + co * o[2*i+1];
      }
#pragma unroll
      for (int i = 0; i < 4; ++i)
        *(float4*)&KB[lane][wg * 16 + 4 * i] = make_float4(ko[4*i], ko[4*i+1], ko[4*i+2], ko[4*i+3]);
    }
    __syncthreads();   // B3: K + q published
    // scores + softmax fused (unchanged)
    {
      const int t0 = tid & 7;
      const int i  = (tid >> 3) & 3;
      const int h  = tid >> 5;
      const int r  = tid >> 3;
      float4 qa = *(const float4*)&qb[i][h * 8];
      float4 qc = *(const float4*)&qb[i][h * 8 + 4];
      float v[6];
#pragma unroll
      for (int j = 0; j < 6; ++j) {
        int t = t0 + 8 * j;
        float4 ka = *(const float4*)&KB[t][h * 8];
        float4 kc = *(const float4*)&KB[t][h * 8 + 4];
        float a = qa.x * ka.x + qa.y * ka.y + qa.z * ka.z + qa.w * ka.w
                + qc.x * kc.x + qc.y * kc.y + qc.z * kc.z + qc.w * kc.w;
        v[j] = a * scale - db[t];
      }
      float m = fmaxf(fmaxf(fmaxf(v[0], v[1]), fmaxf(v[2], v[3])), fmaxf(v[4], v[5]));
      m = fmaxf(m, __shfl_xor(m, 1));
      m = fmaxf(m, __shfl_xor(m, 2));
      m = fmaxf(m, __shfl_xor(m, 4));
      float sum = 0.f;
#pragma unroll
      for (int j = 0; j < 6; ++j) { v[j] = __expf(v[j] - m); sum += v[j]; }
      sum += __shfl_xor(sum, 1);
      sum += __shfl_xor(sum, 2);
      sum += __shfl_xor(sum, 4);
      float inv = 1.f / sum;
#pragma unroll
      for (int j = 0; j < 6; ++j) scb[r][t0 + 8 * j] = v[j] * inv;
    }
    __syncthreads();   // B4: probs published; fences KB reads before T writes
    // T = a @ ctx  (32 x 64), rows grp+4m -> KB (wave-local mod-4 rows)
    {
      float acc[8];
#pragma unroll
      for (int m = 0; m < 8; ++m) acc[m] = 0.f;
      for (int tt = 0; tt < 48; tt += 4) {
        float e0 = embs[(tt + 0) * 68 + lane], e1 = embs[(tt + 1) * 68 + lane];
        float e2 = embs[(tt + 2) * 68 + lane], e3 = embs[(tt + 3) * 68 + lane];
#pragma unroll
        for (int m = 0; m < 8; ++m) {
          float4 sc4 = *(const float4*)&scb[grp + 4 * m][tt];
          acc[m] += sc4.x * e0 + sc4.y * e1 + sc4.z * e2 + sc4.w * e3;
        }
      }
#pragma unroll
      for (int m = 0; m < 8; ++m) KB[grp + 4 * m][lane] = acc[m];
    }
    // no barrier: wave grp reads exactly rows ≡ grp (mod 4) it just wrote
    {
      const int r = ((lane >> 3) << 2) + grp;
      float a = 0.f;
      for (int c = 0; c < 64; c += 4) {
        float4 tv = *(const float4*)&KB[r][c];
        a += tv.x * Wv_p[(c + 0) * 64 + lane] + tv.y * Wv_p[(c + 1) * 64 + lane]
           + tv.z * Wv_p[(c + 2) * 64 + lane] + tv.w * Wv_p[(c + 3) * 64 + lane];
      }
      qb[grp][lane] = a;
    }
    // no barrier: qb row grp wave-local
    {
      float a = Hs[grp][lane];
      for (int k = 0; k < 64; k += 4) {
        float4 av = *(const float4*)&qb[grp][k];
        a += av.x * Wo_p[(k + 0) * 64 + lane] + av.y * Wo_p[(k + 1) * 64 + lane]
           + av.z * Wo_p[(k + 2) * 64 + lane] + av.w * Wo_p[(k + 3) * 64 + lane];
      }
      Hs[grp][lane] = a;
    }
    if (l == 0) __syncthreads();   // B5a: Wv reads of KB done before l=1 K writes
  }

  // ---- final cross attention
  const float* Wq2_p = Wq2 + (s << 12);
  const float* Wk2_p = Wk2 + (s << 12);
  const float* Wv2_p = Wv2 + (s << 12);
  const float* Wo2_p = Wo2 + (s << 12);
  if (tid < 64) {
    float a = 0.f;
    for (int k = 0; k < 64; k += 4) {
      float4 cv = *(const float4*)&embs[48 * 68 + k];
      a += cv.x * Wq2_p[(k + 0) * 64 + lane] + cv.y * Wq2_p[(k + 1) * 64 + lane]
         + cv.z * Wq2_p[(k + 2) * 64 + lane] + cv.w * Wq2_p[(k + 3) * 64 + lane];
    }
    float other = __shfl_xor(a, 1);
    int p = (lane >> 1) & 3;
    float co = cs8T[p][48], si = cs8T[4 + p][48];
    q2[lane] = (lane & 1) ? (si * other + co * a) : (co * a - si * other);
  }
  {
    float aK = 0.f, aV = 0.f;
    for (int k = 0; k < 64; k += 4) {
      float4 hv = *(const float4*)&Hs[grp][k];
      aK += hv.x * Wk2_p[(k + 0) * 64 + lane] + hv.y * Wk2_p[(k + 1) * 64 + lane]
          + hv.z * Wk2_p[(k + 2) * 64 + lane] + hv.w * Wk2_p[(k + 3) * 64 + lane];
      aV += hv.x * Wv2_p[(k + 0) * 64 + lane] + hv.y * Wv2_p[(k + 1) * 64 + lane]
          + hv.z * Wv2_p[(k + 2) * 64 + lane] + hv.w * Wv2_p[(k + 3) * 64 + lane];
    }
    KB[grp][lane] = aK;      // k2 rows 0..3
    KB[8 + grp][lane] = aV;  // v2 rows 8..11
  }
  __syncthreads();   // B5: k2/v2 + q2 published for wave 0
  if (tid < 32) {
    int h = tid >> 2, i = tid & 3;
    float a = 0.f;
#pragma unroll
    for (int d = 0; d < 8; ++d) a += q2[h * 8 + d] * KB[i][h * 8 + d];
    a *= scale;
    float m = fmaxf(a, __shfl_xor(a, 1));
    m = fmaxf(m, __shfl_xor(m, 2));
    float e = __expf(a - m);
    float sum = e + __shfl_xor(e, 1);
    sum += __shfl_xor(sum, 2);
    a2[tid] = e / sum;
  }
  // wave-0 local from here
  if (tid < 64) {
    int h = lane >> 3;
    float a = 0.f;
#pragma unroll
    for (int i = 0; i < 4; ++i) a += a2[h * 4 + i] * KB[8 + i][lane];
    o1[lane] = a;
  }
  if (tid < 64) {
    float a = 0.f;
    for (int k = 0; k < 64; k += 4) {
      float4 ov = *(const float4*)&o1[k];
      a += ov.x * Wo2_p[(k + 0) * 64 + lane] + ov.y * Wo2_p[(k + 1) * 64 + lane]
         + ov.z * Wo2_p[(k + 2) * 64 + lane] + ov.w * Wo2_p[(k + 3) * 64 + lane];
    }
    enc[b * 138 + s * 64 + lane] = a;
  }
}

// ---------------- decoder: enc(138) -> 512 -> 256 -> 1, 8 batches/block ----
__global__ __launch_bounds__(256, 5) void k_dec(
    const float* __restrict__ enc,
    const float* __restrict__ w0, const float* __restrict__ b0,
    const float* __restrict__ w1, const float* __restrict__ b1,
    const float* __restrict__ w2, const float* __restrict__ b2,
    float* __restrict__ out)
{
  __shared__ float encs[8][140];
  __shared__ float h0s[8][512];
  __shared__ float h1s[8][256];
  const int tid = threadIdx.x;
  const int rb = blockIdx.x * 8;

  for (int i = tid; i < 8 * 138; i += 256) {
    int r = i / 138, k = i - r * 138;
    encs[r][k] = enc[(rb + r) * 138 + k];
  }
  __syncthreads();
  {
    float acc0[8], acc1[8];
    const float bb0 = b0[tid], bb1 = b0[tid + 256];
#pragma unroll
    for (int r = 0; r < 8; ++r) { acc0[r] = bb0; acc1[r] = bb1; }
    for (int k = 0; k < 136; k += 4) {
      float wa0 = w0[(k + 0) * 512 + tid], wa1 = w0[(k + 1) * 512 + tid];
      float wa2 = w0[(k + 2) * 512 + tid], wa3 = w0[(k + 3) * 512 + tid];
      float wb0 = w0[(k + 0) * 512 + tid + 256], wb1 = w0[(k + 1) * 512 + tid + 256];
      float wb2 = w0[(k + 2) * 512 + tid + 256], wb3 = w0[(k + 3) * 512 + tid + 256];
#pragma unroll
      for (int r = 0; r < 8; ++r) {
        float4 ev = *(const float4*)&encs[r][k];
        acc0[r] += ev.x * wa0 + ev.y * wa1 + ev.z * wa2 + ev.w * wa3;
        acc1[r] += ev.x * wb0 + ev.y * wb1 + ev.z * wb2 + ev.w * wb3;
      }
    }
    for (int k = 136; k < 138; ++k) {
      float wa = w0[k * 512 + tid], wb = w0[k * 512 + tid + 256];
#pragma unroll
      for (int r = 0; r < 8; ++r) {
        float e = encs[r][k];
        acc0[r] += e * wa; acc1[r] += e * wb;
      }
    }
#pragma unroll
    for (int r = 0; r < 8; ++r) {
      h0s[r][tid] = tanhshrink_f(acc0[r]);
      h0s[r][tid + 256] = tanhshrink_f(acc1[r]);
    }
  }
  __syncthreads();
  {
    float acc[8];
    const float bb = b1[tid];
#pragma unroll
    for (int r = 0; r < 8; ++r) acc[r] = bb;
    for (int k = 0; k < 512; k += 4) {
      float ww0 = w1[(k + 0) * 256 + tid], ww1 = w1[(k + 1) * 256 + tid];
      float ww2 = w1[(k + 2) * 256 + tid], ww3 = w1[(k + 3) * 256 + tid];
#pragma unroll
      for (int r = 0; r < 8; ++r) {
        float4 hv = *(const float4*)&h0s[r][k];
        acc[r] += hv.x * ww0 + hv.y * ww1 + hv.z * ww2 + hv.w * ww3;
      }
    }
#pragma unroll
    for (int r = 0; r < 8; ++r) h1s[r][tid] = tanhshrink_f(acc[r]);
  }
  __syncthreads();
  {
    int r = tid >> 5, l32 = tid & 31;
    float a = 0.f;
#pragma unroll
    for (int kk = 0; kk < 8; ++kk) {
      int k = l32 + 32 * kk;
      a += h1s[r][k] * w2[k];
    }
    for (int off = 16; off; off >>= 1) a += __shfl_down(a, off, 32);
    if (l32 == 0) out[rb + r] = a + b2[0];
  }
}

extern "C" void kernel_launch(void* const* d_in, const int* in_sizes, int n_in,
                              void* d_out, int out_size, void* d_ws, size_t ws_size,
                              hipStream_t stream) {
  const float* inp        = (const float*)d_in[0];
  const float* dists      = (const float*)d_in[1];
  const float* bn_gamma   = (const float*)d_in[3];
  const float* bn_beta    = (const float*)d_in[4];
  const float* xe_w1      = (const float*)d_in[5];
  const float* xe_b1      = (const float*)d_in[6];
  const float* xe_w2      = (const float*)d_in[7];
  const float* xe_b2      = (const float*)d_in[8];
  const float* ye_w1      = (const float*)d_in[9];
  const float* ye_b1      = (const float*)d_in[10];
  const float* ye_w2      = (const float*)d_in[11];
  const float* ye_b2      = (const float*)d_in[12];
  const float* learnable  = (const float*)d_in[13];
  const float* hidden     = (const float*)d_in[14];
  const float* Wq         = (const float*)d_in[15];
  const float* Wk         = (const float*)d_in[16];
  const float* Wv         = (const float*)d_in[17];
  const float* Wo         = (const float*)d_in[18];
  const float* Wq2        = (const float*)d_in[19];
  const float* Wk2        = (const float*)d_in[20];
  const float* Wv2        = (const float*)d_in[21];
  const float* Wo2        = (const float*)d_in[22];
  const float* dec_w0     = (const float*)d_in[23];
  const float* dec_b0     = (const float*)d_in[24];
  const float* dec_w1     = (const float*)d_in[25];
  const float* dec_b1     = (const float*)d_in[26];
  const float* dec_w2     = (const float*)d_in[27];
  const float* dec_b2     = (const float*)d_in[28];

  double* gsum = (double*)d_ws;                       // 18 doubles @ 0
  float*  bnp  = (float*)((char*)d_ws + 256);         // 18 floats
  float*  q0g  = (float*)((char*)d_ws + 512);         // 512 floats
  float*  enc  = (float*)((char*)d_ws + 2560);        // 8192*138 floats -> ends 4524544
  float*  xw1T = (float*)((char*)d_ws + 4524544);     // 512 floats   (2048 B)
  float*  we2  = (float*)((char*)d_ws + 4526592);     // 8192 floats  (32768 B)
  float*  wk4  = (float*)((char*)d_ws + 4559360);     // 16384 floats (65536 B) -> ends 4624896

  hipMemsetAsync(d_ws, 0, 256, stream);
  k_stats   <<<512, 256, 0, stream>>>(inp, gsum);
  k_finalize<<<1, 256, 0, stream>>>(gsum, bn_gamma, bn_beta, hidden, Wq,
                                    xe_w1, xe_w2, ye_w2, Wk,
                                    bnp, q0g, xw1T, we2, wk4);
  k_mega    <<<BS * 2, 256, 0, stream>>>(inp, dists, bnp, q0g,
                                         xw1T, xe_b1, we2, xe_b2,
                                         ye_w1, ye_b1, ye_b2,
                                         learnable, hidden,
                                         Wq, wk4, Wv, Wo, Wq2, Wk2, Wv2, Wo2, enc);
  k_dec     <<<BS / 8, 256, 0, stream>>>(enc, dec_w0, dec_b0, dec_w1, dec_b1,
                                         dec_w2, dec_b2, (float*)d_out);
}